// Round 1
// baseline (2403.827 us; speedup 1.0000x reference)
//
#include <hip/hip_runtime.h>

#define TPB 256

// ---- degree ----
__global__ void k_deg_init(int* deg, int n) {
    int i = blockIdx.x * blockDim.x + threadIdx.x;
    if (i < n) deg[i] = 1;  // self-loop
}

__global__ void k_deg_count(const int* __restrict__ dst, int* deg, int E) {
    int i = blockIdx.x * blockDim.x + threadIdx.x;
    if (i < E) atomicAdd(&deg[dst[i]], 1);
}

// ---- layer 1 transform: dis = rsqrt(deg); h0s = (x @ W1) * dis; agg1 seeded with h0s (self-loop) ----
__global__ void k_l1(const float* __restrict__ x, const float* __restrict__ W1,
                     float* dis_deg, float* __restrict__ h0s, float* __restrict__ agg1, int n) {
    __shared__ float sW[192];  // 12x16
    int t = threadIdx.x;
    if (t < 192) sW[t] = W1[t];
    __syncthreads();
    int v = blockIdx.x * blockDim.x + t;
    if (v >= n) return;
    int degv = ((const int*)dis_deg)[v];
    float d = rsqrtf((float)degv);
    dis_deg[v] = d;
    const float4* xp = (const float4*)(x + (size_t)v * 12);
    float4 a = xp[0], b = xp[1], c = xp[2];
    float xi[12] = {a.x, a.y, a.z, a.w, b.x, b.y, b.z, b.w, c.x, c.y, c.z, c.w};
    float out[16];
#pragma unroll
    for (int j = 0; j < 16; j++) {
        float acc = 0.f;
#pragma unroll
        for (int k = 0; k < 12; k++) acc = fmaf(xi[k], sW[k * 16 + j], acc);
        out[j] = acc * d;
    }
    float4* hp = (float4*)(h0s + (size_t)v * 16);
    float4* gp = (float4*)(agg1 + (size_t)v * 16);
#pragma unroll
    for (int j = 0; j < 4; j++) {
        float4 vv = make_float4(out[4 * j], out[4 * j + 1], out[4 * j + 2], out[4 * j + 3]);
        hp[j] = vv;
        gp[j] = vv;
    }
}

// ---- layer 1 edge scatter: 16 lanes per edge ----
__global__ void k_edge1(const int* __restrict__ es, const int* __restrict__ ed,
                        const float* __restrict__ h0s, float* agg1, int E) {
    int tid = blockIdx.x * blockDim.x + threadIdx.x;
    int e = tid >> 4;
    if (e >= E) return;
    int c = tid & 15;
    int s = es[e], d = ed[e];
    unsafeAtomicAdd(&agg1[(size_t)d * 16 + c], h0s[(size_t)s * 16 + c]);
}

// ---- layer 2 transform: h1 = relu(dis*agg1 + b1); h2s = (h1 @ W2) * dis; agg2 seeded ----
__global__ void k_l2(const float* __restrict__ agg1, const float* __restrict__ dis,
                     const float* __restrict__ W2, const float* __restrict__ b1,
                     float* __restrict__ h2s, float* __restrict__ agg2, int n) {
    __shared__ float sW[128];  // 16x8
    __shared__ float sb[16];
    int t = threadIdx.x;
    if (t < 128) sW[t] = W2[t];
    if (t < 16) sb[t] = b1[t];
    __syncthreads();
    int v = blockIdx.x * blockDim.x + t;
    if (v >= n) return;
    float d = dis[v];
    const float4* ap = (const float4*)(agg1 + (size_t)v * 16);
    float h1[16];
#pragma unroll
    for (int j = 0; j < 4; j++) {
        float4 q = ap[j];
        h1[4 * j + 0] = fmaxf(fmaf(d, q.x, sb[4 * j + 0]), 0.f);
        h1[4 * j + 1] = fmaxf(fmaf(d, q.y, sb[4 * j + 1]), 0.f);
        h1[4 * j + 2] = fmaxf(fmaf(d, q.z, sb[4 * j + 2]), 0.f);
        h1[4 * j + 3] = fmaxf(fmaf(d, q.w, sb[4 * j + 3]), 0.f);
    }
    float out[8];
#pragma unroll
    for (int j = 0; j < 8; j++) {
        float acc = 0.f;
#pragma unroll
        for (int k = 0; k < 16; k++) acc = fmaf(h1[k], sW[k * 8 + j], acc);
        out[j] = acc * d;
    }
    float4* hp = (float4*)(h2s + (size_t)v * 8);
    float4* gp = (float4*)(agg2 + (size_t)v * 8);
#pragma unroll
    for (int j = 0; j < 2; j++) {
        float4 vv = make_float4(out[4 * j], out[4 * j + 1], out[4 * j + 2], out[4 * j + 3]);
        hp[j] = vv;
        gp[j] = vv;
    }
}

// ---- layer 2 edge scatter: 8 lanes per edge ----
__global__ void k_edge2(const int* __restrict__ es, const int* __restrict__ ed,
                        const float* __restrict__ h2s, float* agg2, int E) {
    int tid = blockIdx.x * blockDim.x + threadIdx.x;
    int e = tid >> 3;
    if (e >= E) return;
    int c = tid & 7;
    int s = es[e], d = ed[e];
    unsafeAtomicAdd(&agg2[(size_t)d * 8 + c], h2s[(size_t)s * 8 + c]);
}

// ---- epilogue ----
__global__ void k_out(const float* __restrict__ agg2, const float* __restrict__ dis,
                      const float* __restrict__ b2, float* __restrict__ out, int n) {
    int tid = blockIdx.x * blockDim.x + threadIdx.x;
    if (tid >= n * 8) return;
    int v = tid >> 3;
    int c = tid & 7;
    out[tid] = fmaf(dis[v], agg2[tid], b2[c]);
}

extern "C" void kernel_launch(void* const* d_in, const int* in_sizes, int n_in,
                              void* d_out, int out_size, void* d_ws, size_t ws_size,
                              hipStream_t stream) {
    const float* x  = (const float*)d_in[0];
    const int*   ei = (const int*)d_in[1];
    const float* W1 = (const float*)d_in[2];
    const float* b1 = (const float*)d_in[3];
    const float* W2 = (const float*)d_in[4];
    const float* b2 = (const float*)d_in[5];
    float* out = (float*)d_out;

    int n = in_sizes[0] / 12;
    int E = in_sizes[1] / 2;
    const int* es = ei;       // edge_index[0] = src
    const int* ed = ei + E;   // edge_index[1] = dst

    float* ws = (float*)d_ws;
    float* deg_dis = ws;                       // n floats (int during counting)
    float* h0s  = ws + (size_t)n;              // 16n
    float* agg1 = ws + (size_t)17 * n;         // 16n
    float* h2s  = ws + (size_t)33 * n;         // 8n
    float* agg2 = ws + (size_t)41 * n;         // 8n

    int nb_n = (n + TPB - 1) / TPB;
    k_deg_init<<<nb_n, TPB, 0, stream>>>((int*)deg_dis, n);
    k_deg_count<<<(E + TPB - 1) / TPB, TPB, 0, stream>>>(ed, (int*)deg_dis, E);
    k_l1<<<nb_n, TPB, 0, stream>>>(x, W1, deg_dis, h0s, agg1, n);
    long long t1 = (long long)E * 16;
    k_edge1<<<(t1 + TPB - 1) / TPB, TPB, 0, stream>>>(es, ed, h0s, agg1, E);
    k_l2<<<nb_n, TPB, 0, stream>>>(agg1, deg_dis, W2, b1, h2s, agg2, n);
    long long t2 = (long long)E * 8;
    k_edge2<<<(t2 + TPB - 1) / TPB, TPB, 0, stream>>>(es, ed, h2s, agg2, E);
    long long t3 = (long long)n * 8;
    k_out<<<(t3 + TPB - 1) / TPB, TPB, 0, stream>>>(agg2, deg_dis, b2, out, n);
}